// Round 1
// 100.822 us; speedup vs baseline: 1.3477x; 1.3477x over previous
//
#include <hip/hip_runtime.h>

#define B_   8
#define N_   307
#define BN   (B_ * N_)          // 2456 blocks
#define OUT_ELEMS (BN * 64 * 64)

typedef float f32x4 __attribute__((ext_vector_type(4)));
typedef short s16x8 __attribute__((ext_vector_type(8)));

__device__ __forceinline__ unsigned short f2bf(float x) {
    unsigned int u = __builtin_bit_cast(unsigned int, x);
    u += 0x7FFFu + ((u >> 16) & 1u);        // round-to-nearest-even
    return (unsigned short)(u >> 16);
}

// XOR-swizzle on 16B frag rows (G4 / m201 pattern): spreads row bits 3..5
// into bank bits. Bijective within each 8-row block; applied to ALL frag
// buffer accesses (writes + reads) so layouts stay consistent.
__device__ __forceinline__ int swz(int row) { return row ^ ((row >> 3) & 7); }

__device__ __forceinline__ s16x8 ldfrag(const unsigned short* p) {
    return *reinterpret_cast<const s16x8*>(p);
}

// 64x64 row-major fp32 -> bf16 A-operand fragment layout (swizzled rows)
__device__ __forceinline__ void stage_A(const float* __restrict__ src,
                                        unsigned short* dst, int tid) {
    const float4* s4 = reinterpret_cast<const float4*>(src);
#pragma unroll
    for (int i = 0; i < 4; ++i) {
        int idx = i * 256 + tid;          // float4 index, 1024 total
        float4 v = s4[idx];
        int m  = idx >> 4;
        int f0 = (idx & 15) << 2;
        int mt = m >> 4;
        int ki = f0 >> 5;
        int qd = (f0 >> 3) & 3;
        int j0 = f0 & 7;                  // 0 or 4
        int row = (mt * 2 + ki) * 64 + (qd << 4) + (m & 15);
        unsigned short* p = dst + (swz(row) << 3) + j0;
        short4 pk;
        pk.x = (short)f2bf(v.x); pk.y = (short)f2bf(v.y);
        pk.z = (short)f2bf(v.z); pk.w = (short)f2bf(v.w);
        *reinterpret_cast<short4*>(p) = pk;
    }
}

// 64x64 row-major fp32 (K x N) -> bf16 B-operand fragment layout (swizzled)
__device__ __forceinline__ void stage_B(const float* __restrict__ src,
                                        unsigned short* dst, int tid) {
    const float4* s4 = reinterpret_cast<const float4*>(src);
#pragma unroll
    for (int i = 0; i < 4; ++i) {
        int idx = i * 256 + tid;
        float4 v = s4[idx];
        int k  = idx >> 4;
        int n0 = (idx & 15) << 2;
        int ki = k >> 5;
        int qd = (k >> 3) & 3;
        int j  = k & 7;
        float vv[4] = {v.x, v.y, v.z, v.w};
#pragma unroll
        for (int c = 0; c < 4; ++c) {
            int n = n0 + c;
            int row = ((n >> 4) * 2 + ki) * 64 + (qd << 4) + (n & 15);
            dst[(swz(row) << 3) + j] = f2bf(vv[c]);
        }
    }
}

__global__ __launch_bounds__(256, 4) void mta_kernel(
    const float* __restrict__ Xq, const float* __restrict__ Xk,
    const float* __restrict__ Xv, const float* __restrict__ maskp,
    const float* __restrict__ res, const float* __restrict__ Wq,
    const float* __restrict__ Wk, const float* __restrict__ Wv,
    const float* __restrict__ Wfc, const float* __restrict__ lnS,
    const float* __restrict__ lnB, float* __restrict__ out,
    float* __restrict__ scores_out)
{
    // 40KB LDS exactly -> 4 blocks/CU (was 58.5KB -> 2 blocks/CU).
    // res_att staging + score tile + reductions moved to registers;
    // cross-wave softmax combine buffers alias the dead sXC region.
    __shared__ __align__(16) unsigned char smem[40960];
    unsigned short* sQf = (unsigned short*)(smem);           // 8KB scores A-frags
    unsigned short* sKf = (unsigned short*)(smem + 8192);    // 8KB scores B-frags
    unsigned short* sVf = (unsigned short*)(smem + 16384);   // 8KB PV B-frags
    unsigned short* sXC = (unsigned short*)(smem + 24576);   // 8KB X frags (proj) / ctx frags (fc)
    unsigned short* sWA = (unsigned short*)(smem + 32768);   // 8KB W frags / attn A-frags
    // aliased into sXC while it is dead (attention phase):
    float* wM = (float*)(smem + 24576);                      // [k=64][w=4] per-wave col max
    float* wS = (float*)(smem + 25600);                      // [k=64][w=4] per-wave col expsum

    const int bn   = blockIdx.x;
    const int tid  = threadIdx.x;
    const int w    = tid >> 6;       // wave = row mtile
    const int lane = tid & 63;
    const int quad = lane >> 4;
    const int l16  = lane & 15;
    const size_t base64 = (size_t)bn * 4096;

    // ---------------- Projections: Q (scaled 1/4), K, V ----------------
#pragma unroll 1
    for (int pj = 0; pj < 3; ++pj) {
        const float* Xs = (pj == 0) ? Xq : (pj == 1) ? Xk : Xv;
        const float* Ws = (pj == 0) ? Wq : (pj == 1) ? Wk : Wv;
        stage_A(Xs + base64, sXC, tid);
        stage_B(Ws, sWA, tid);
        __syncthreads();
        s16x8 a0 = ldfrag(sXC + (swz((w * 2 + 0) * 64 + lane) << 3));
        s16x8 a1 = ldfrag(sXC + (swz((w * 2 + 1) * 64 + lane) << 3));
#pragma unroll
        for (int nt = 0; nt < 4; ++nt) {
            f32x4 acc = {0.f, 0.f, 0.f, 0.f};
            s16x8 b0 = ldfrag(sWA + (swz((nt * 2 + 0) * 64 + lane) << 3));
            s16x8 b1 = ldfrag(sWA + (swz((nt * 2 + 1) * 64 + lane) << 3));
            acc = __builtin_amdgcn_mfma_f32_16x16x32_bf16(a0, b0, acc, 0, 0, 0);
            acc = __builtin_amdgcn_mfma_f32_16x16x32_bf16(a1, b1, acc, 0, 0, 0);
            if (pj == 0) {          // Q -> scores A-frag layout, fold 1/sqrt(16)
#pragma unroll
                for (int r = 0; r < 4; ++r) {
                    int rowq = (nt * 4 + w) * 32 + ((l16 >> 3) << 4) + quad * 4 + r;
                    sQf[(swz(rowq) << 3) + (l16 & 7)] = f2bf(acc[r] * 0.25f);
                }
            } else if (pj == 1) {   // K -> scores B-frag layout
#pragma unroll
                for (int r = 0; r < 4; ++r) {
                    int rowk = (nt * 4 + w) * 32 + ((l16 >> 3) << 4) + quad * 4 + r;
                    sKf[(swz(rowk) << 3) + (l16 & 7)] = f2bf(acc[r]);
                }
            } else {                // V -> PV B-frag layout (nt == head)
#pragma unroll
                for (int r = 0; r < 4; ++r) {
                    int kk = w * 16 + quad * 4 + r;
                    int rowv = (nt * 2 + (kk >> 5)) * 64 + (((kk >> 3) & 3) << 4) + l16;
                    sVf[(swz(rowv) << 3) + (kk & 7)] = f2bf(acc[r]);
                }
            }
        }
        __syncthreads();
    }

    // mask per q row, held in registers (4 broadcast loads, L1/L2 hot)
    bool bm[4];
#pragma unroll
    for (int r = 0; r < 4; ++r)
        bm[r] = maskp[bn * 64 + w * 16 + quad * 4 + r] > 0.5f;

    // ---------------- Attention (per head, fully unrolled: ctx statically indexed) ----------------
    f32x4 ctx[4];
#pragma unroll
    for (int h = 0; h < 4; ++h) ctx[h] = {0.f, 0.f, 0.f, 0.f};

    const s16x8 zf = {0, 0, 0, 0, 0, 0, 0, 0};
#pragma unroll
    for (int h = 0; h < 4; ++h) {
        const size_t sbase = ((size_t)(bn * 4 + h)) << 12;

        // res_att -> registers in MFMA C layout (no LDS staging; 64B segments)
        float resv[4][4];
#pragma unroll
        for (int nt = 0; nt < 4; ++nt)
#pragma unroll
            for (int r = 0; r < 4; ++r)
                resv[nt][r] = res[sbase + (w * 16 + quad * 4 + r) * 64 + nt * 16 + l16];

        // scores = (Q/4)·K^T + res ; K=16 zero-padded to 32 (lanes>=32 zero frags)
        s16x8 aq = zf;
        if (lane < 32) aq = ldfrag(sQf + (swz((h * 4 + w) * 32 + lane) << 3));
        float sv[4][4];
#pragma unroll
        for (int nt = 0; nt < 4; ++nt) {
            s16x8 bk = zf;
            if (lane < 32) bk = ldfrag(sKf + (swz((h * 4 + nt) * 32 + lane) << 3));
            f32x4 t = {0.f, 0.f, 0.f, 0.f};
            t = __builtin_amdgcn_mfma_f32_16x16x32_bf16(aq, bk, t, 0, 0, 0);
#pragma unroll
            for (int r = 0; r < 4; ++r) sv[nt][r] = t[r] + resv[nt][r];
        }

        // mask whole q row + direct global store of masked scores (64B segments)
#pragma unroll
        for (int nt = 0; nt < 4; ++nt)
#pragma unroll
            for (int r = 0; r < 4; ++r) {
                float s = bm[r] ? -1e9f : sv[nt][r];
                scores_out[sbase + (w * 16 + quad * 4 + r) * 64 + nt * 16 + l16] = s;
                sv[nt][r] = s;
            }

        // column softmax over q (axis=3): in-thread(r) -> cross-quad shfl -> cross-wave LDS
        float Mw[4], Sw[4];
#pragma unroll
        for (int nt = 0; nt < 4; ++nt) {
            float m0 = fmaxf(fmaxf(sv[nt][0], sv[nt][1]), fmaxf(sv[nt][2], sv[nt][3]));
            m0 = fmaxf(m0, __shfl_xor(m0, 16, 64));
            m0 = fmaxf(m0, __shfl_xor(m0, 32, 64));
            float e0 = 0.f;
#pragma unroll
            for (int r = 0; r < 4; ++r) { sv[nt][r] = __expf(sv[nt][r] - m0); e0 += sv[nt][r]; }
            e0 += __shfl_xor(e0, 16, 64);
            e0 += __shfl_xor(e0, 32, 64);
            Mw[nt] = m0; Sw[nt] = e0;
        }
        if (quad == 0) {
#pragma unroll
            for (int nt = 0; nt < 4; ++nt) {
                wM[(nt * 16 + l16) * 4 + w] = Mw[nt];
                wS[(nt * 16 + l16) * 4 + w] = Sw[nt];
            }
        }
        __syncthreads();   // also orders prev head's PV reads before sWA reuse below

        // combine 4 per-wave partials, rescale, write attn -> PV A-frag layout
#pragma unroll
        for (int nt = 0; nt < 4; ++nt) {
            int k = nt * 16 + l16;
            float4 vm = *reinterpret_cast<float4*>(&wM[k * 4]);
            float4 vs = *reinterpret_cast<float4*>(&wS[k * 4]);
            float M = fmaxf(fmaxf(vm.x, vm.y), fmaxf(vm.z, vm.w));
            float S = vs.x * __expf(vm.x - M) + vs.y * __expf(vm.y - M)
                    + vs.z * __expf(vm.z - M) + vs.w * __expf(vm.w - M);
            float fs = __expf(Mw[nt] - M) / S;
            int rw = (w * 2 + (k >> 5)) * 64 + (((k >> 3) & 3) << 4) + quad * 4;
#pragma unroll
            for (int r = 0; r < 4; ++r)
                sWA[(swz(rw + r) << 3) + (k & 7)] = f2bf(sv[nt][r] * fs);
        }
        __syncthreads();

        // PV: ctx_h += attn · V_h
#pragma unroll
        for (int ki = 0; ki < 2; ++ki) {
            s16x8 ap = ldfrag(sWA + (swz((w * 2 + ki) * 64 + lane) << 3));
            s16x8 bv = ldfrag(sVf + (swz((h * 2 + ki) * 64 + lane) << 3));
            ctx[h] = __builtin_amdgcn_mfma_f32_16x16x32_bf16(ap, bv, ctx[h], 0, 0, 0);
        }
        // no trailing barrier: next head's softmax barrier orders sWA reuse
    }
    __syncthreads();   // protect sXC/sWA before fc staging (waits last PV reads)

    // ---------------- fc + residual + layernorm ----------------
#pragma unroll
    for (int h = 0; h < 4; ++h) {
        int c    = h * 16 + l16;
        int rowb = (w * 2 + (c >> 5)) * 64 + (((c >> 3) & 3) << 4) + quad * 4;
#pragma unroll
        for (int r = 0; r < 4; ++r)
            sXC[(swz(rowb + r) << 3) + (c & 7)] = f2bf(ctx[h][r]);
    }
    stage_B(Wfc, sWA, tid);
    __syncthreads();

    f32x4 oacc[4];
    {
        s16x8 a0 = ldfrag(sXC + (swz((w * 2 + 0) * 64 + lane) << 3));
        s16x8 a1 = ldfrag(sXC + (swz((w * 2 + 1) * 64 + lane) << 3));
#pragma unroll
        for (int nt = 0; nt < 4; ++nt) {
            f32x4 acc = {0.f, 0.f, 0.f, 0.f};
            s16x8 b0 = ldfrag(sWA + (swz((nt * 2 + 0) * 64 + lane) << 3));
            s16x8 b1 = ldfrag(sWA + (swz((nt * 2 + 1) * 64 + lane) << 3));
            acc = __builtin_amdgcn_mfma_f32_16x16x32_bf16(a0, b0, acc, 0, 0, 0);
            acc = __builtin_amdgcn_mfma_f32_16x16x32_bf16(a1, b1, acc, 0, 0, 0);
            oacc[nt] = acc;
        }
    }

    float scl[4], bia[4];
#pragma unroll
    for (int nt = 0; nt < 4; ++nt) {
        scl[nt] = lnS[nt * 16 + l16];
        bia[nt] = lnB[nt * 16 + l16];
    }
#pragma unroll
    for (int r = 0; r < 4; ++r) {
        int q = w * 16 + quad * 4 + r;
        float px[4], sum = 0.f, sq = 0.f;
#pragma unroll
        for (int nt = 0; nt < 4; ++nt) {
            float x = oacc[nt][r] + Xq[base64 + q * 64 + nt * 16 + l16];
            px[nt] = x; sum += x; sq += x * x;
        }
        // row of 64 lives on the 16 lanes of this quad (4 vals each): xor-reduce
#pragma unroll
        for (int m = 1; m <= 8; m <<= 1) {
            sum += __shfl_xor(sum, m, 64);
            sq  += __shfl_xor(sq,  m, 64);
        }
        float mu   = sum * 0.015625f;
        float var  = sq * 0.015625f - mu * mu;
        float rstd = rsqrtf(var + 1e-5f);
#pragma unroll
        for (int nt = 0; nt < 4; ++nt) {
            out[base64 + q * 64 + nt * 16 + l16] = (px[nt] - mu) * rstd * scl[nt] + bia[nt];
        }
    }
}

extern "C" void kernel_launch(void* const* d_in, const int* in_sizes, int n_in,
                              void* d_out, int out_size, void* d_ws, size_t ws_size,
                              hipStream_t stream) {
    const float* Xq   = (const float*)d_in[0];
    const float* Xk   = (const float*)d_in[1];
    const float* Xv   = (const float*)d_in[2];
    const float* msk  = (const float*)d_in[3];
    const float* res  = (const float*)d_in[4];
    const float* Wq   = (const float*)d_in[5];
    const float* Wk   = (const float*)d_in[6];
    const float* Wv   = (const float*)d_in[7];
    const float* Wfc  = (const float*)d_in[8];
    const float* lnS  = (const float*)d_in[9];
    const float* lnB  = (const float*)d_in[10];
    float* out    = (float*)d_out;
    float* scores = out + OUT_ELEMS;
    mta_kernel<<<BN, 256, 0, stream>>>(Xq, Xk, Xv, msk, res, Wq, Wk, Wv, Wfc,
                                       lnS, lnB, out, scores);
}